// Round 10
// baseline (168.517 us; speedup 1.0000x reference)
//
#include <hip/hip_runtime.h>
#include <hip/hip_bf16.h>

#define Tn 512
#define Bn 512
#define Kn 128

typedef __bf16 bf16_t;
typedef __bf16 bf16x8 __attribute__((ext_vector_type(8)));
typedef float f32x4 __attribute__((ext_vector_type(4)));
typedef unsigned int u32;
typedef u32 u32x2 __attribute__((ext_vector_type(2)));
typedef u32 u32x4 __attribute__((ext_vector_type(4)));

#define NEXPEM 4096   // expem blocks in fused pre-kernel

__device__ __forceinline__ u32 pack2bf(float a, float b) {
    bf16_t ha = (bf16_t)a, hb = (bf16_t)b;
    u32 ua = (u32)__builtin_bit_cast(unsigned short, ha);
    u32 ub = (u32)__builtin_bit_cast(unsigned short, hb);
    return ua | (ub << 16);
}

// ---------------- fused pre: expem (blocks 0..4095) + numerator (4096..4607)
//                  + frag build / zeroing (block 4608) ----------------
// A-frag image: idx = (((dir*8 + m)*4 + ks)*64 + l)*8 + e
//   lane roles: c=l&15, g=l>>4;  k = 32*ks + 8*g + e
//   row j = J(m,c) = 32*(m>>1) + 4*(m&1) + 8*(c>>2) + (c&3)
//   dir 0 (fwd): A[j][k] = exp(trans[k][j]);  dir 1 (bwd): A[j][k] = exp(trans[j][k])
// J chosen so D's per-lane output IS the next step's B-frag layout (verified r1-r9).
template<int PRE>
__global__ __launch_bounds__(256)
void crf_pre(const float* __restrict__ em, const int* __restrict__ tags,
             const int* __restrict__ mask, const float* __restrict__ startT,
             const float* __restrict__ endT, const float* __restrict__ trans,
             u32* __restrict__ X, bf16_t* __restrict__ frags,
             float* __restrict__ num, float* __restrict__ out, int* __restrict__ done)
{
    const int bid = blockIdx.x;
    const int tid = threadIdx.x;

    if (bid < NEXPEM) {                 // ---- expem: X = bf16(exp(em)) ----
        if (!PRE) return;
        const size_t N = (size_t)Tn * Bn * Kn;
        const size_t nth = (size_t)NEXPEM * 256;
        for (size_t base = ((size_t)bid * 256 + tid) * 8; base < N; base += nth * 8) {
            const f32x4 a = *reinterpret_cast<const f32x4*>(em + base);
            const f32x4 b = *reinterpret_cast<const f32x4*>(em + base + 4);
            u32x4 w;
            w[0] = pack2bf(__expf(a[0]), __expf(a[1]));
            w[1] = pack2bf(__expf(a[2]), __expf(a[3]));
            w[2] = pack2bf(__expf(b[0]), __expf(b[1]));
            w[3] = pack2bf(__expf(b[2]), __expf(b[3]));
            *reinterpret_cast<u32x4*>(X + base / 2) = w;
        }
        return;
    }

    const int b = bid - NEXPEM;
    if (b == Bn) {                      // ---- frags + zero out/done ----
        if (tid == 0) out[0] = 0.f;
        if (tid < 32) done[tid] = 0;
        for (int idx = tid; idx < 2*8*4*64*8; idx += blockDim.x) {
            const int e   = idx & 7;
            const int l   = (idx >> 3) & 63;
            const int ks  = (idx >> 9) & 3;
            const int m   = (idx >> 11) & 7;
            const int dir = (idx >> 14) & 1;
            const int c = l & 15, g = l >> 4;
            const int k = 32*ks + 8*g + e;
            const int j = 32*(m >> 1) + 4*(m & 1) + 8*(c >> 2) + (c & 3);
            const float v = (dir == 0) ? trans[k*Kn + j] : trans[j*Kn + k];
            frags[idx] = (bf16_t)__expf(v);
        }
        return;
    }

    // ---- numerator for batch b (256 threads) ----
    float s = 0.f;
    int cnt = 0;
    for (int t = tid; t < Tn; t += 256) {
        const int mk = mask[t*Bn + b];
        cnt += (mk != 0);
        if (t >= 1 && mk != 0) {
            const int tp = tags[(t-1)*Bn + b];
            const int tc = tags[t*Bn + b];
            s += trans[tp*Kn + tc] + em[(size_t)t*Bn*Kn + (size_t)b*Kn + tc];
        }
    }
    __shared__ float sred[256];
    __shared__ int   cred[256];
    sred[tid] = s; cred[tid] = cnt;
    __syncthreads();
    for (int off = 128; off > 0; off >>= 1) {
        if (tid < off) { sred[tid] += sred[tid+off]; cred[tid] += cred[tid+off]; }
        __syncthreads();
    }
    if (tid == 0) {
        const int t0tag = tags[b];
        const float n0 = startT[t0tag] + em[(size_t)b*Kn + t0tag];
        int seq_end = cred[0] - 1;
        if (seq_end < 0) seq_end = 0;
        const int lastTag = tags[seq_end*Bn + b];
        num[b] = n0 + sred[0] + endT[lastTag];
    }
}

// ---------------- main: 8-wave j-split recurrence (r8 body) + fused combine tail ----
// 64 blocks x 512 threads (8 waves = 2 waves/SIMD on 64 CUs). Wave mw owns m-tile mw
// (4 chained MFMA), produces 4 j's/lane (u32x2 b64 write). State exchange: 8KB
// double-buffered LDS, one raw s_barrier/step. Incremental per-lane pointers
// (r8-verified 810cy/step). After the final store, the second-arriving block of each
// batch group computes the combine inline (device-scope done[] handshake).
template<int PRE>
__global__ __launch_bounds__(512, 1)
void crf_main(const float* __restrict__ em, const u32* __restrict__ Xp,
              const int* __restrict__ maskp,
              const float* __restrict__ startT, const float* __restrict__ endT,
              const bf16_t* __restrict__ frags,
              float* __restrict__ vws, float* __restrict__ Cws,
              const float* __restrict__ num, float* __restrict__ out,
              int* __restrict__ done)
{
    const int bid = blockIdx.x;          // 64 blocks
    const int dir = bid & 1;
    const int grp = bid >> 1;            // batch group 0..31
    const int b0  = grp * 16;
    const int tid = threadIdx.x;
    const int mw  = tid >> 6;            // wave id = m-tile index 0..7
    const int l   = tid & 63;
    const int c = l & 15, g = l >> 4;
    const int batch = b0 + c;
    const int ksw  = mw >> 1, half = mw & 1;
    const int bj   = 32*ksw + 4*half;    // base j of own 4 outputs (plus 8g)

    __shared__ __align__(16) u32x4 exchg[2][4][64];   // [parity][slice][lane]
    __shared__ int who;

    // resident E fragments for own m-tile
    bf16x8 af[4];
    {
        const bf16_t* fb = frags + (size_t)dir * 16384;
        #pragma unroll
        for (int ks = 0; ks < 4; ++ks)
            af[ks] = *reinterpret_cast<const bf16x8*>(fb + ((mw*4 + ks)*64 + l)*8);
    }

    // init own state (+ bwd f32 state)
    f32x4 up;
    u32 ownprev0, ownprev1;
    float Cacc = 0.f;
    {
        const float* sv = dir ? endT : startT;
        const int t0 = dir ? 511 : 0;
        const f32x4 e4 = *reinterpret_cast<const f32x4*>(
            em + ((size_t)t0*Bn + batch)*Kn + bj + 8*g);
        const float* s4p = sv + bj + 8*g;
        f32x4 y;
        #pragma unroll
        for (int r = 0; r < 4; ++r) {
            const float s = s4p[r];
            y[r]  = __expf(s + e4[r]);
            up[r] = __expf(s);
        }
        ownprev0 = pack2bf(y[0], y[1]);
        ownprev1 = pack2bf(y[2], y[3]);
        u32* slot = reinterpret_cast<u32*>(&exchg[1][ksw][l]) + 2*half;
        u32x2 nw2 = {ownprev0, ownprev1};
        *reinterpret_cast<u32x2*>(slot) = nw2;   // iter m=1 reads parity 1
    }

    const int M = 256 - dir;

    // incremental per-buffer pointers (each advances 2 t per use; always in-bounds)
    const int xstep_pre = dir ? -(Bn*Kn)     : (Bn*Kn);       // u32 units / 2t
    const int xstep_f32 = dir ? -(2*Bn*Kn)   : (2*Bn*Kn);     // f32 units / 2t
    const int mstep     = dir ? -(2*Bn)      : (2*Bn);        // int units / 2t
    const u32 *pXA, *pXB; const float *pEA, *pEB; const int *pMA, *pMB;
    {
        const int tA  = dir ? 510 : 1, tB  = dir ? 509 : 2;
        const int tmA = dir ? 511 : 1, tmB = dir ? 510 : 2;
        pXA = Xp + (((size_t)tA*Bn + batch)*Kn >> 1) + ((bj + 8*g) >> 1);
        pXB = Xp + (((size_t)tB*Bn + batch)*Kn >> 1) + ((bj + 8*g) >> 1);
        pEA = em + ((size_t)tA*Bn + batch)*Kn + bj + 8*g;
        pEB = em + ((size_t)tB*Bn + batch)*Kn + bj + 8*g;
        pMA = maskp + (size_t)tmA*Bn + batch;
        pMB = maskp + (size_t)tmB*Bn + batch;
    }

    u32x2 xA, xB; f32x4 eA, eB; int mkA, mkB;
    auto load_tile = [&](u32x2& xd, f32x4& ed, int& mk,
                         const u32*& pX, const float*& pE, const int*& pM) {
        if (PRE) { xd = *reinterpret_cast<const u32x2*>(pX); pX += xstep_pre; }
        else     { ed = *reinterpret_cast<const f32x4*>(pE); pE += xstep_f32; }
        mk = *pM; pM += mstep;
    };

    auto iter = [&](u32x2& xcur, f32x4& ecur, int& mkcur,
                    const u32*& pX, const float*& pE, const int*& pM, bool rs, int par) {
        // release own write of previous step, sync, read full state
        asm volatile("s_waitcnt lgkmcnt(0)" ::: "memory");
        __builtin_amdgcn_s_barrier();
        __builtin_amdgcn_sched_barrier(0);

        const u32x4 bs0 = exchg[par][0][l];
        const u32x4 bs1 = exchg[par][1][l];
        const u32x4 bs2 = exchg[par][2][l];
        const u32x4 bs3 = exchg[par][3][l];

        f32x4 acc = {0.f, 0.f, 0.f, 0.f};
        acc = __builtin_amdgcn_mfma_f32_16x16x32_bf16(af[0], __builtin_bit_cast(bf16x8, bs0), acc, 0, 0, 0);
        acc = __builtin_amdgcn_mfma_f32_16x16x32_bf16(af[1], __builtin_bit_cast(bf16x8, bs1), acc, 0, 0, 0);
        acc = __builtin_amdgcn_mfma_f32_16x16x32_bf16(af[2], __builtin_bit_cast(bf16x8, bs2), acc, 0, 0, 0);
        acc = __builtin_amdgcn_mfma_f32_16x16x32_bf16(af[3], __builtin_bit_cast(bf16x8, bs3), acc, 0, 0, 0);

        const bool mk = (mkcur != 0);
        float sc = 1.f, klog = 0.f;
        if (rs) {   // exact pow-2 rescale; exponent of batch c's k=0 state component
            int ex = (int)((bs0[0] >> 7) & 0xFF) - 127;
            ex = __shfl(ex, c, 64);
            sc = __uint_as_float((u32)((127 - ex) & 0xFF) << 23);
            klog = (float)ex * 0.6931471805599453f;
        }

        f32x4 xf;
        if (PRE) {
            xf[0] = __uint_as_float(xcur[0] << 16);
            xf[1] = __uint_as_float(xcur[0] & 0xffff0000u);
            xf[2] = __uint_as_float(xcur[1] << 16);
            xf[3] = __uint_as_float(xcur[1] & 0xffff0000u);
        } else {
            #pragma unroll
            for (int r = 0; r < 4; ++r) xf[r] = __expf(ecur[r]);
        }

        u32 nw0, nw1;
        if (dir == 0) {  // fwd: v_t = (v@E)*x_t if mask else v
            f32x4 y;
            #pragma unroll
            for (int r = 0; r < 4; ++r) {
                float a = acc[r];
                if (rs) a *= sc;
                y[r] = a * xf[r];
            }
            nw0 = pack2bf(y[0], y[1]);
            nw1 = pack2bf(y[2], y[3]);
            nw0 = mk ? nw0 : ownprev0;
            nw1 = mk ? nw1 : ownprev1;
            ownprev0 = nw0; ownprev1 = nw1;
            if (rs && mk) Cacc += klog;
        } else {  // bwd: u = select(E@B, u); scale both branches; B = u*x_t
            f32x4 y;
            #pragma unroll
            for (int r = 0; r < 4; ++r) {
                float un = mk ? acc[r] : up[r];
                if (rs) un *= sc;
                up[r] = un;
                y[r] = un * xf[r];
            }
            nw0 = pack2bf(y[0], y[1]);
            nw1 = pack2bf(y[2], y[3]);
            if (rs) Cacc += klog;
        }

        u32* slot = reinterpret_cast<u32*>(&exchg[par ^ 1][ksw][l]) + 2*half;
        u32x2 nw2 = {nw0, nw1};
        *reinterpret_cast<u32x2*>(slot) = nw2;

        load_tile(xcur, ecur, mkcur, pX, pE, pM);
        __builtin_amdgcn_sched_barrier(0xF); // ALU/VALU/SALU/MFMA may cross; VMEM+DS pinned
    };

    load_tile(xA, eA, mkA, pXA, pEA, pMA);
    load_tile(xB, eB, mkB, pXB, pEB, pMB);
    __builtin_amdgcn_sched_barrier(0xF);

    int m = 1;
    for (; m + 3 <= M; m += 4) {       // rs static: only (m+3)%4==0 rescales; par static
        iter(xA, eA, mkA, pXA, pEA, pMA, false, 1);
        iter(xB, eB, mkB, pXB, pEB, pMB, false, 0);
        iter(xA, eA, mkA, pXA, pEA, pMA, false, 1);
        iter(xB, eB, mkB, pXB, pEB, pMB, true,  0);
    }
    for (; m <= M; ++m) {              // bwd tail m=253..255 (never a rescale step)
        if (m & 1) iter(xA, eA, mkA, pXA, pEA, pMA, false, 1);
        else       iter(xB, eB, mkB, pXB, pEB, pMB, false, 0);
    }

    // final own state: fwd from ownprev regs, bwd from f32 up
    float* vrow = vws + ((size_t)(dir*Bn + batch))*Kn + bj + 8*g;
    f32x4 fv;
    if (dir) {
        fv = up;
    } else {
        fv[0] = __uint_as_float(ownprev0 << 16);
        fv[1] = __uint_as_float(ownprev0 & 0xffff0000u);
        fv[2] = __uint_as_float(ownprev1 << 16);
        fv[3] = __uint_as_float(ownprev1 & 0xffff0000u);
    }
    *reinterpret_cast<f32x4*>(vrow) = fv;
    if (mw == 0 && g == 0) Cws[dir*Bn + batch] = Cacc;

    // ---- fused combine: second-arriving block of this group does it ----
    __threadfence();                       // release vws/Cws stores
    if (tid == 0) who = atomicAdd(&done[grp], 1);
    __syncthreads();
    if (who == 1) {
        __threadfence();                   // acquire other block's stores
        const int cb   = tid >> 5;         // batch within group 0..15
        const int part = tid & 31;
        const float* vf = vws + (size_t)(b0 + cb)*Kn;
        const float* vu = vws + (size_t)(Bn + b0 + cb)*Kn;
        float s = 0.f;
        #pragma unroll
        for (int r = 0; r < 4; ++r) {
            const int k = part*4 + r;
            s += vf[k] * vu[k];
        }
        #pragma unroll
        for (int o = 16; o > 0; o >>= 1) s += __shfl_xor(s, o, 32);
        if (part == 0) {
            const float den = Cws[b0 + cb] + Cws[Bn + b0 + cb] + logf(s);
            atomicAdd(out, num[b0 + cb] - den);
        }
    }
}

extern "C" void kernel_launch(void* const* d_in, const int* in_sizes, int n_in,
                              void* d_out, int out_size, void* d_ws, size_t ws_size,
                              hipStream_t stream)
{
    const float* em     = (const float*)d_in[0];
    const int*   tags   = (const int*)d_in[1];
    const int*   mask   = (const int*)d_in[2];
    const float* startT = (const float*)d_in[3];
    const float* endT   = (const float*)d_in[4];
    const float* trans  = (const float*)d_in[5];

    const size_t XBYTES = (size_t)Tn * Bn * Kn * 2;               // 33.5 MB
    const size_t SMALL  = 65536 + 2048 + 4096 + 524288 + 256;     // frags+num+Cws+vws+done
    const bool pre = (ws_size >= XBYTES + SMALL);

    char* ws = (char*)d_ws;
    u32*  X  = (u32*)ws;                                    // PRE path only
    char* base = pre ? (ws + XBYTES) : ws;
    bf16_t* frags = (bf16_t*)base;
    float*  num   = (float*)(base + 65536);
    float*  Cws   = (float*)(base + 65536 + 2048);
    float*  vws   = (float*)(base + 65536 + 2048 + 4096);
    int*    done  = (int*)(base + 65536 + 2048 + 4096 + 524288);
    float*  out   = (float*)d_out;

    if (pre) {
        hipLaunchKernelGGL((crf_pre<1>), dim3(NEXPEM + Bn + 1), dim3(256), 0, stream,
                           em, tags, mask, startT, endT, trans, X, frags, num, out, done);
        hipLaunchKernelGGL((crf_main<1>), dim3(64), dim3(512), 0, stream,
                           em, X, mask, startT, endT, frags, vws, Cws, num, out, done);
    } else {
        hipLaunchKernelGGL((crf_pre<0>), dim3(NEXPEM + Bn + 1), dim3(256), 0, stream,
                           em, tags, mask, startT, endT, trans, X, frags, num, out, done);
        hipLaunchKernelGGL((crf_main<0>), dim3(64), dim3(512), 0, stream,
                           em, X, mask, startT, endT, frags, vws, Cws, num, out, done);
    }
}

// Round 11
// 142.906 us; speedup vs baseline: 1.1792x; 1.1792x over previous
//
#include <hip/hip_runtime.h>
#include <hip/hip_bf16.h>

#define Tn 512
#define Bn 512
#define Kn 128

typedef __bf16 bf16_t;
typedef __bf16 bf16x8 __attribute__((ext_vector_type(8)));
typedef float f32x4 __attribute__((ext_vector_type(4)));
typedef unsigned int u32;
typedef u32 u32x2 __attribute__((ext_vector_type(2)));
typedef u32 u32x4 __attribute__((ext_vector_type(4)));

#define NEXPEM 4096   // expem blocks in fused pre-kernel

__device__ __forceinline__ u32 pack2bf(float a, float b) {
    bf16_t ha = (bf16_t)a, hb = (bf16_t)b;
    u32 ua = (u32)__builtin_bit_cast(unsigned short, ha);
    u32 ub = (u32)__builtin_bit_cast(unsigned short, hb);
    return ua | (ub << 16);
}

// ---------------- fused pre: expem (blocks 0..4095) + numerator (4096..4607)
//                  + frag build / zeroing (block 4608) ----------------
// A-frag image: idx = (((dir*8 + m)*4 + ks)*64 + l)*8 + e
//   lane roles: c=l&15, g=l>>4;  k = 32*ks + 8*g + e
//   row j = J(m,c) = 32*(m>>1) + 4*(m&1) + 8*(c>>2) + (c&3)
//   dir 0 (fwd): A[j][k] = exp(trans[k][j]);  dir 1 (bwd): A[j][k] = exp(trans[j][k])
// J chosen so D's per-lane output IS the next step's B-frag layout (verified r1-r10).
template<int PRE>
__global__ __launch_bounds__(256)
void crf_pre(const float* __restrict__ em, const int* __restrict__ tags,
             const int* __restrict__ mask, const float* __restrict__ startT,
             const float* __restrict__ endT, const float* __restrict__ trans,
             u32* __restrict__ X, bf16_t* __restrict__ frags,
             float* __restrict__ num, float* __restrict__ out)
{
    const int bid = blockIdx.x;
    const int tid = threadIdx.x;

    if (bid < NEXPEM) {                 // ---- expem: X = bf16(exp(em)) ----
        if (!PRE) return;
        const size_t N = (size_t)Tn * Bn * Kn;
        const size_t nth = (size_t)NEXPEM * 256;
        for (size_t base = ((size_t)bid * 256 + tid) * 8; base < N; base += nth * 8) {
            const f32x4 a = *reinterpret_cast<const f32x4*>(em + base);
            const f32x4 b = *reinterpret_cast<const f32x4*>(em + base + 4);
            u32x4 w;
            w[0] = pack2bf(__expf(a[0]), __expf(a[1]));
            w[1] = pack2bf(__expf(a[2]), __expf(a[3]));
            w[2] = pack2bf(__expf(b[0]), __expf(b[1]));
            w[3] = pack2bf(__expf(b[2]), __expf(b[3]));
            *reinterpret_cast<u32x4*>(X + base / 2) = w;
        }
        return;
    }

    const int b = bid - NEXPEM;
    if (b == Bn) {                      // ---- frags + zero out ----
        if (tid == 0) out[0] = 0.f;
        for (int idx = tid; idx < 2*8*4*64*8; idx += blockDim.x) {
            const int e   = idx & 7;
            const int l   = (idx >> 3) & 63;
            const int ks  = (idx >> 9) & 3;
            const int m   = (idx >> 11) & 7;
            const int dir = (idx >> 14) & 1;
            const int c = l & 15, g = l >> 4;
            const int k = 32*ks + 8*g + e;
            const int j = 32*(m >> 1) + 4*(m & 1) + 8*(c >> 2) + (c & 3);
            const float v = (dir == 0) ? trans[k*Kn + j] : trans[j*Kn + k];
            frags[idx] = (bf16_t)__expf(v);
        }
        return;
    }

    // ---- numerator for batch b (256 threads) ----
    float s = 0.f;
    int cnt = 0;
    for (int t = tid; t < Tn; t += 256) {
        const int mk = mask[t*Bn + b];
        cnt += (mk != 0);
        if (t >= 1 && mk != 0) {
            const int tp = tags[(t-1)*Bn + b];
            const int tc = tags[t*Bn + b];
            s += trans[tp*Kn + tc] + em[(size_t)t*Bn*Kn + (size_t)b*Kn + tc];
        }
    }
    __shared__ float sred[256];
    __shared__ int   cred[256];
    sred[tid] = s; cred[tid] = cnt;
    __syncthreads();
    for (int off = 128; off > 0; off >>= 1) {
        if (tid < off) { sred[tid] += sred[tid+off]; cred[tid] += cred[tid+off]; }
        __syncthreads();
    }
    if (tid == 0) {
        const int t0tag = tags[b];
        const float n0 = startT[t0tag] + em[(size_t)b*Kn + t0tag];
        int seq_end = cred[0] - 1;
        if (seq_end < 0) seq_end = 0;
        const int lastTag = tags[seq_end*Bn + b];
        num[b] = n0 + sred[0] + endT[lastTag];
    }
}

// ---------------- main: 8-wave j-split recurrence (r9 body, NO combine tail) ----------
// 64 blocks x 512 threads (8 waves = 2 waves/SIMD on 64 CUs). Wave mw owns m-tile mw
// (4 MFMA as 2 independent 2-chains + add), produces 4 j's/lane (u32x2 b64 write).
// State exchange: 8KB double-buffered LDS, one raw s_barrier/step. t-advance via
// uniform (SALU) offsets + constant per-lane 32-bit offsets. Combine is a separate
// kernel: the fused tail perturbed loop codegen (+20-33us, r9/r10 A/B).
template<int PRE>
__global__ __launch_bounds__(512, 1)
void crf_main(const float* __restrict__ em, const u32* __restrict__ Xp,
              const int* __restrict__ maskp,
              const float* __restrict__ startT, const float* __restrict__ endT,
              const bf16_t* __restrict__ frags,
              float* __restrict__ vws, float* __restrict__ Cws)
{
    const int bid = blockIdx.x;          // 64 blocks
    const int dir = bid & 1;
    const int b0  = (bid >> 1) * 16;
    const int tid = threadIdx.x;
    const int mw  = tid >> 6;            // wave id = m-tile index 0..7
    const int l   = tid & 63;
    const int c = l & 15, g = l >> 4;
    const int batch = b0 + c;
    const int ksw  = mw >> 1, half = mw & 1;
    const int bj   = 32*ksw + 4*half;    // base j of own 4 outputs (plus 8g)

    __shared__ __align__(16) u32x4 exchg[2][4][64];   // [parity][slice][lane]

    // resident E fragments for own m-tile
    bf16x8 af[4];
    {
        const bf16_t* fb = frags + (size_t)dir * 16384;
        #pragma unroll
        for (int ks = 0; ks < 4; ++ks)
            af[ks] = *reinterpret_cast<const bf16x8*>(fb + ((mw*4 + ks)*64 + l)*8);
    }

    // init own state (+ bwd f32 state)
    f32x4 up;
    u32 ownprev0, ownprev1;
    float Cacc = 0.f;
    {
        const float* sv = dir ? endT : startT;
        const int t0 = dir ? 511 : 0;
        const f32x4 e4 = *reinterpret_cast<const f32x4*>(
            em + ((size_t)t0*Bn + batch)*Kn + bj + 8*g);
        const float* s4p = sv + bj + 8*g;
        f32x4 y;
        #pragma unroll
        for (int r = 0; r < 4; ++r) {
            const float s = s4p[r];
            y[r]  = __expf(s + e4[r]);
            up[r] = __expf(s);
        }
        ownprev0 = pack2bf(y[0], y[1]);
        ownprev1 = pack2bf(y[2], y[3]);
        u32* slot = reinterpret_cast<u32*>(&exchg[1][ksw][l]) + 2*half;
        u32x2 nw2 = {ownprev0, ownprev1};
        *reinterpret_cast<u32x2*>(slot) = nw2;   // iter m=1 reads parity 1
    }

    const int M = 256 - dir;

    // constant per-lane offsets (32-bit) + uniform t-offsets advanced on SALU
    const u32 laneX = (u32)(((batch*Kn) + bj + 8*g) >> 1);   // u32-index into X
    const u32 laneE = (u32)((batch*Kn) + bj + 8*g);          // f32-index into em
    const u32 laneM = (u32)batch;                            // int-index into mask
    const long stepX = dir ? -(long)(Bn*Kn)   : (long)(Bn*Kn);     // per 2t (u32 units)
    const long stepE = dir ? -(long)(2*Bn*Kn) : (long)(2*Bn*Kn);   // per 2t (f32 units)
    const long stepM = dir ? -(long)(2*Bn)    : (long)(2*Bn);      // per 2t (int units)
    long uXA, uXB, uEA, uEB, uMA, uMB;
    {
        const int tA  = dir ? 510 : 1, tB  = dir ? 509 : 2;
        const int tmA = dir ? 511 : 1, tmB = dir ? 510 : 2;
        uXA = (long)tA * (Bn*Kn/2);  uXB = (long)tB * (Bn*Kn/2);
        uEA = (long)tA * (Bn*Kn);    uEB = (long)tB * (Bn*Kn);
        uMA = (long)tmA * Bn;        uMB = (long)tmB * Bn;
    }

    u32x2 xA, xB; f32x4 eA, eB; int mkA, mkB;
    auto load_tile = [&](u32x2& xd, f32x4& ed, int& mk, long& uX, long& uE, long& uM) {
        if (PRE) { xd = *reinterpret_cast<const u32x2*>(Xp + uX + laneX); uX += stepX; }
        else     { ed = *reinterpret_cast<const f32x4*>(em + uE + laneE); uE += stepE; }
        mk = maskp[uM + laneM]; uM += stepM;
    };

    auto iter = [&](u32x2& xcur, f32x4& ecur, int& mkcur,
                    long& uX, long& uE, long& uM, bool rs, int par) {
        // release own write of previous step, sync, read full state
        asm volatile("s_waitcnt lgkmcnt(0)" ::: "memory");
        __builtin_amdgcn_s_barrier();
        __builtin_amdgcn_sched_barrier(0);

        const u32x4 bs0 = exchg[par][0][l];
        const u32x4 bs1 = exchg[par][1][l];
        const u32x4 bs2 = exchg[par][2][l];
        const u32x4 bs3 = exchg[par][3][l];

        // 2 independent MFMA chains of 2, then add (halves serial MFMA latency)
        f32x4 a0 = {0.f, 0.f, 0.f, 0.f}, a1 = {0.f, 0.f, 0.f, 0.f};
        a0 = __builtin_amdgcn_mfma_f32_16x16x32_bf16(af[0], __builtin_bit_cast(bf16x8, bs0), a0, 0, 0, 0);
        a1 = __builtin_amdgcn_mfma_f32_16x16x32_bf16(af[2], __builtin_bit_cast(bf16x8, bs2), a1, 0, 0, 0);
        a0 = __builtin_amdgcn_mfma_f32_16x16x32_bf16(af[1], __builtin_bit_cast(bf16x8, bs1), a0, 0, 0, 0);
        a1 = __builtin_amdgcn_mfma_f32_16x16x32_bf16(af[3], __builtin_bit_cast(bf16x8, bs3), a1, 0, 0, 0);
        const f32x4 acc = a0 + a1;

        const bool mk = (mkcur != 0);
        float sc = 1.f, klog = 0.f;
        if (rs) {   // exact pow-2 rescale; exponent of batch c's k=0 state component
            int ex = (int)((bs0[0] >> 7) & 0xFF) - 127;
            ex = __shfl(ex, c, 64);
            sc = __uint_as_float((u32)((127 - ex) & 0xFF) << 23);
            klog = (float)ex * 0.6931471805599453f;
        }

        f32x4 xf;
        if (PRE) {
            xf[0] = __uint_as_float(xcur[0] << 16);
            xf[1] = __uint_as_float(xcur[0] & 0xffff0000u);
            xf[2] = __uint_as_float(xcur[1] << 16);
            xf[3] = __uint_as_float(xcur[1] & 0xffff0000u);
        } else {
            #pragma unroll
            for (int r = 0; r < 4; ++r) xf[r] = __expf(ecur[r]);
        }

        u32 nw0, nw1;
        if (dir == 0) {  // fwd: v_t = (v@E)*x_t if mask else v
            f32x4 y;
            #pragma unroll
            for (int r = 0; r < 4; ++r) {
                float a = acc[r];
                if (rs) a *= sc;
                y[r] = a * xf[r];
            }
            nw0 = pack2bf(y[0], y[1]);
            nw1 = pack2bf(y[2], y[3]);
            nw0 = mk ? nw0 : ownprev0;
            nw1 = mk ? nw1 : ownprev1;
            ownprev0 = nw0; ownprev1 = nw1;
            if (rs && mk) Cacc += klog;
        } else {  // bwd: u = select(E@B, u); scale both branches; B = u*x_t
            f32x4 y;
            #pragma unroll
            for (int r = 0; r < 4; ++r) {
                float un = mk ? acc[r] : up[r];
                if (rs) un *= sc;
                up[r] = un;
                y[r] = un * xf[r];
            }
            nw0 = pack2bf(y[0], y[1]);
            nw1 = pack2bf(y[2], y[3]);
            if (rs) Cacc += klog;
        }

        u32* slot = reinterpret_cast<u32*>(&exchg[par ^ 1][ksw][l]) + 2*half;
        u32x2 nw2 = {nw0, nw1};
        *reinterpret_cast<u32x2*>(slot) = nw2;

        load_tile(xcur, ecur, mkcur, uX, uE, uM);
        __builtin_amdgcn_sched_barrier(0xF); // ALU/VALU/SALU/MFMA may cross; VMEM+DS pinned
    };

    load_tile(xA, eA, mkA, uXA, uEA, uMA);
    load_tile(xB, eB, mkB, uXB, uEB, uMB);
    __builtin_amdgcn_sched_barrier(0xF);

    int m = 1;
    for (; m + 3 <= M; m += 4) {       // rs static: only (m+3)%4==0 rescales; par static
        iter(xA, eA, mkA, uXA, uEA, uMA, false, 1);
        iter(xB, eB, mkB, uXB, uEB, uMB, false, 0);
        iter(xA, eA, mkA, uXA, uEA, uMA, false, 1);
        iter(xB, eB, mkB, uXB, uEB, uMB, true,  0);
    }
    for (; m <= M; ++m) {              // bwd tail m=253..255 (never a rescale step)
        if (m & 1) iter(xA, eA, mkA, uXA, uEA, uMA, false, 1);
        else       iter(xB, eB, mkB, uXB, uEB, uMB, false, 0);
    }

    // final own state: fwd from ownprev regs, bwd from f32 up
    float* vrow = vws + ((size_t)(dir*Bn + batch))*Kn + bj + 8*g;
    f32x4 fv;
    if (dir) {
        fv = up;
    } else {
        fv[0] = __uint_as_float(ownprev0 << 16);
        fv[1] = __uint_as_float(ownprev0 & 0xffff0000u);
        fv[2] = __uint_as_float(ownprev1 << 16);
        fv[3] = __uint_as_float(ownprev1 & 0xffff0000u);
    }
    *reinterpret_cast<f32x4*>(vrow) = fv;
    if (mw == 0 && g == 0) Cws[dir*Bn + batch] = Cacc;
}

// ---------------- combine: den = Cf + Cb + log(a_256 . u_256); out += num - den ----------------
__global__ void crf_combine(const float* __restrict__ vws, const float* __restrict__ Cws,
                            const float* __restrict__ num, float* __restrict__ out)
{
    const int b = blockIdx.x;
    const int tid = threadIdx.x;
    const float p = vws[(size_t)b*Kn + tid] * vws[(size_t)(Bn + b)*Kn + tid];
    __shared__ float red[128];
    red[tid] = p;
    __syncthreads();
    for (int off = 64; off > 0; off >>= 1) {
        if (tid < off) red[tid] += red[tid + off];
        __syncthreads();
    }
    if (tid == 0) {
        const float den = Cws[b] + Cws[Bn + b] + logf(red[0]);
        atomicAdd(out, num[b] - den);
    }
}

extern "C" void kernel_launch(void* const* d_in, const int* in_sizes, int n_in,
                              void* d_out, int out_size, void* d_ws, size_t ws_size,
                              hipStream_t stream)
{
    const float* em     = (const float*)d_in[0];
    const int*   tags   = (const int*)d_in[1];
    const int*   mask   = (const int*)d_in[2];
    const float* startT = (const float*)d_in[3];
    const float* endT   = (const float*)d_in[4];
    const float* trans  = (const float*)d_in[5];

    const size_t XBYTES = (size_t)Tn * Bn * Kn * 2;               // 33.5 MB
    const size_t SMALL  = 65536 + 2048 + 4096 + 524288;           // frags+num+Cws+vws
    const bool pre = (ws_size >= XBYTES + SMALL);

    char* ws = (char*)d_ws;
    u32*  X  = (u32*)ws;                                    // PRE path only
    char* base = pre ? (ws + XBYTES) : ws;
    bf16_t* frags = (bf16_t*)base;
    float*  num   = (float*)(base + 65536);
    float*  Cws   = (float*)(base + 65536 + 2048);
    float*  vws   = (float*)(base + 65536 + 2048 + 4096);
    float*  out   = (float*)d_out;

    if (pre) {
        hipLaunchKernelGGL((crf_pre<1>), dim3(NEXPEM + Bn + 1), dim3(256), 0, stream,
                           em, tags, mask, startT, endT, trans, X, frags, num, out);
        hipLaunchKernelGGL((crf_main<1>), dim3(64), dim3(512), 0, stream,
                           em, X, mask, startT, endT, frags, vws, Cws);
    } else {
        hipLaunchKernelGGL((crf_pre<0>), dim3(NEXPEM + Bn + 1), dim3(256), 0, stream,
                           em, tags, mask, startT, endT, trans, X, frags, num, out);
        hipLaunchKernelGGL((crf_main<0>), dim3(64), dim3(512), 0, stream,
                           em, X, mask, startT, endT, frags, vws, Cws);
    }
    hipLaunchKernelGGL(crf_combine, dim3(Bn), dim3(128), 0, stream,
                       vws, Cws, num, out);
}

// Round 12
// 124.796 us; speedup vs baseline: 1.3503x; 1.1451x over previous
//
#include <hip/hip_runtime.h>
#include <hip/hip_bf16.h>

#define Tn 512
#define Bn 512
#define Kn 128
#define NUMCH 16   // numerator t-chunks (32 t each)

typedef __bf16 bf16_t;
typedef __bf16 bf16x8 __attribute__((ext_vector_type(8)));
typedef float f32x4 __attribute__((ext_vector_type(4)));
typedef unsigned int u32;
typedef u32 u32x2 __attribute__((ext_vector_type(2)));
typedef u32 u32x4 __attribute__((ext_vector_type(4)));

__device__ __forceinline__ u32 pack2bf(float a, float b) {
    bf16_t ha = (bf16_t)a, hb = (bf16_t)b;
    u32 ua = (u32)__builtin_bit_cast(unsigned short, ha);
    u32 ub = (u32)__builtin_bit_cast(unsigned short, hb);
    return ua | (ub << 16);
}

// ---------------- pre: numerator partials (blocks 0..31, coalesced) +
//                  frag build (blocks 32..159) + out zeroing ----------------
// A-frag image: idx = (((dir*8 + m)*4 + ks)*64 + l)*8 + e
//   lane roles: c=l&15, g=l>>4;  k = 32*ks + 8*g + e
//   row j = J(m,c) = 32*(m>>1) + 4*(m&1) + 8*(c>>2) + (c&3)
//   dir 0 (fwd): A[j][k] = exp(trans[k][j]);  dir 1 (bwd): A[j][k] = exp(trans[j][k])
// J chosen so D's per-lane output IS the next step's B-frag layout (verified r1-r11).
__global__ __launch_bounds__(256)
void crf_pre(const float* __restrict__ em, const int* __restrict__ tags,
             const int* __restrict__ mask, const float* __restrict__ trans,
             bf16_t* __restrict__ frags, float* __restrict__ numpart,
             int* __restrict__ cntpart, float* __restrict__ out)
{
    const int bid = blockIdx.x;
    const int tid = threadIdx.x;

    if (bid < 2*NUMCH) {               // ---- numerator partials, coalesced over b ----
        const int ch = bid >> 1, bh = bid & 1;
        const int b  = bh*256 + tid;   // lane-adjacent b -> coalesced mask/tags loads
        const int t0 = ch * (Tn / NUMCH);
        float s = 0.f;
        int cnt = 0;
        int tagprev = (t0 > 0) ? tags[(t0-1)*Bn + b] : 0;
        for (int t = t0; t < t0 + Tn/NUMCH; ++t) {
            const int mk = mask[t*Bn + b];
            const int tagcur = tags[t*Bn + b];
            if (mk != 0) {
                cnt++;
                if (t >= 1)
                    s += trans[tagprev*Kn + tagcur]
                       + em[(size_t)t*Bn*Kn + (size_t)b*Kn + tagcur];
            }
            tagprev = tagcur;
        }
        numpart[ch*Bn + b] = s;
        cntpart[ch*Bn + b] = cnt;
        return;
    }

    // ---- frag build: 128 blocks x 256 threads = 32768 elements ----
    if (bid == 2*NUMCH && tid == 0) out[0] = 0.f;
    const int idx = (bid - 2*NUMCH)*256 + tid;
    const int e   = idx & 7;
    const int l   = (idx >> 3) & 63;
    const int ks  = (idx >> 9) & 3;
    const int m   = (idx >> 11) & 7;
    const int dir = (idx >> 14) & 1;
    const int c = l & 15, g = l >> 4;
    const int k = 32*ks + 8*g + e;
    const int j = 32*(m >> 1) + 4*(m & 1) + 8*(c >> 2) + (c & 3);
    const float v = (dir == 0) ? trans[k*Kn + j] : trans[j*Kn + k];
    frags[idx] = (bf16_t)__expf(v);
}

// ---------------- main: 8-wave j-split recurrence, in-loop exp (no X) ----------------
// 64 blocks x 512 threads (8 waves = 2 waves/SIMD on 64 CUs). Wave mw owns m-tile mw
// (4 MFMA as 2 independent 2-chains + add), produces 4 j's/lane (u32x2 b64 write).
// State exchange: 8KB double-buffered LDS, one raw s_barrier/step. t-advance via
// uniform (SALU) offsets + constant per-lane 32-bit offsets. 4 expf/step/wave folds
// exp(em) inline (X deleted: at 8-wave split the exp is ~30cy, overlappable).
__global__ __launch_bounds__(512, 1)
void crf_main(const float* __restrict__ em, const int* __restrict__ maskp,
              const float* __restrict__ startT, const float* __restrict__ endT,
              const bf16_t* __restrict__ frags,
              float* __restrict__ vws, float* __restrict__ Cws)
{
    const int bid = blockIdx.x;          // 64 blocks
    const int dir = bid & 1;
    const int b0  = (bid >> 1) * 16;
    const int tid = threadIdx.x;
    const int mw  = tid >> 6;            // wave id = m-tile index 0..7
    const int l   = tid & 63;
    const int c = l & 15, g = l >> 4;
    const int batch = b0 + c;
    const int ksw  = mw >> 1, half = mw & 1;
    const int bj   = 32*ksw + 4*half;    // base j of own 4 outputs (plus 8g)

    __shared__ __align__(16) u32x4 exchg[2][4][64];   // [parity][slice][lane]

    // resident E fragments for own m-tile
    bf16x8 af[4];
    {
        const bf16_t* fb = frags + (size_t)dir * 16384;
        #pragma unroll
        for (int ks = 0; ks < 4; ++ks)
            af[ks] = *reinterpret_cast<const bf16x8*>(fb + ((mw*4 + ks)*64 + l)*8);
    }

    // init own state (+ bwd f32 state)
    f32x4 up;
    u32 ownprev0, ownprev1;
    float Cacc = 0.f;
    {
        const float* sv = dir ? endT : startT;
        const int t0 = dir ? 511 : 0;
        const f32x4 e4 = *reinterpret_cast<const f32x4*>(
            em + ((size_t)t0*Bn + batch)*Kn + bj + 8*g);
        const float* s4p = sv + bj + 8*g;
        f32x4 y;
        #pragma unroll
        for (int r = 0; r < 4; ++r) {
            const float s = s4p[r];
            y[r]  = __expf(s + e4[r]);
            up[r] = __expf(s);
        }
        ownprev0 = pack2bf(y[0], y[1]);
        ownprev1 = pack2bf(y[2], y[3]);
        u32* slot = reinterpret_cast<u32*>(&exchg[1][ksw][l]) + 2*half;
        u32x2 nw2 = {ownprev0, ownprev1};
        *reinterpret_cast<u32x2*>(slot) = nw2;   // iter m=1 reads parity 1
    }

    const int M = 256 - dir;

    // constant per-lane offsets (32-bit) + uniform t-offsets advanced on SALU
    const u32 laneE = (u32)((batch*Kn) + bj + 8*g);          // f32-index into em
    const u32 laneM = (u32)batch;                            // int-index into mask
    const long stepE = dir ? -(long)(2*Bn*Kn) : (long)(2*Bn*Kn);   // per 2t (f32 units)
    const long stepM = dir ? -(long)(2*Bn)    : (long)(2*Bn);      // per 2t (int units)
    long uEA, uEB, uMA, uMB;
    {
        const int tA  = dir ? 510 : 1, tB  = dir ? 509 : 2;
        const int tmA = dir ? 511 : 1, tmB = dir ? 510 : 2;
        uEA = (long)tA * (Bn*Kn);    uEB = (long)tB * (Bn*Kn);
        uMA = (long)tmA * Bn;        uMB = (long)tmB * Bn;
    }

    f32x4 eA, eB; int mkA, mkB;
    auto load_tile = [&](f32x4& ed, int& mk, long& uE, long& uM) {
        ed = *reinterpret_cast<const f32x4*>(em + uE + laneE); uE += stepE;
        mk = maskp[uM + laneM]; uM += stepM;
    };

    auto iter = [&](f32x4& ecur, int& mkcur, long& uE, long& uM, bool rs, int par) {
        // release own write of previous step, sync, read full state
        asm volatile("s_waitcnt lgkmcnt(0)" ::: "memory");
        __builtin_amdgcn_s_barrier();
        __builtin_amdgcn_sched_barrier(0);

        const u32x4 bs0 = exchg[par][0][l];
        const u32x4 bs1 = exchg[par][1][l];
        const u32x4 bs2 = exchg[par][2][l];
        const u32x4 bs3 = exchg[par][3][l];

        // 2 independent MFMA chains of 2, then add (halves serial MFMA latency)
        f32x4 a0 = {0.f, 0.f, 0.f, 0.f}, a1 = {0.f, 0.f, 0.f, 0.f};
        a0 = __builtin_amdgcn_mfma_f32_16x16x32_bf16(af[0], __builtin_bit_cast(bf16x8, bs0), a0, 0, 0, 0);
        a1 = __builtin_amdgcn_mfma_f32_16x16x32_bf16(af[2], __builtin_bit_cast(bf16x8, bs2), a1, 0, 0, 0);
        a0 = __builtin_amdgcn_mfma_f32_16x16x32_bf16(af[1], __builtin_bit_cast(bf16x8, bs1), a0, 0, 0, 0);
        a1 = __builtin_amdgcn_mfma_f32_16x16x32_bf16(af[3], __builtin_bit_cast(bf16x8, bs3), a1, 0, 0, 0);
        const f32x4 acc = a0 + a1;

        const bool mk = (mkcur != 0);
        float sc = 1.f, klog = 0.f;
        if (rs) {   // exact pow-2 rescale; exponent of batch c's k=0 state component
            int ex = (int)((bs0[0] >> 7) & 0xFF) - 127;
            ex = __shfl(ex, c, 64);
            sc = __uint_as_float((u32)((127 - ex) & 0xFF) << 23);
            klog = (float)ex * 0.6931471805599453f;
        }

        f32x4 xf;
        #pragma unroll
        for (int r = 0; r < 4; ++r) xf[r] = __expf(ecur[r]);

        u32 nw0, nw1;
        if (dir == 0) {  // fwd: v_t = (v@E)*x_t if mask else v
            f32x4 y;
            #pragma unroll
            for (int r = 0; r < 4; ++r) {
                float a = acc[r];
                if (rs) a *= sc;
                y[r] = a * xf[r];
            }
            nw0 = pack2bf(y[0], y[1]);
            nw1 = pack2bf(y[2], y[3]);
            nw0 = mk ? nw0 : ownprev0;
            nw1 = mk ? nw1 : ownprev1;
            ownprev0 = nw0; ownprev1 = nw1;
            if (rs && mk) Cacc += klog;
        } else {  // bwd: u = select(E@B, u); scale both branches; B = u*x_t
            f32x4 y;
            #pragma unroll
            for (int r = 0; r < 4; ++r) {
                float un = mk ? acc[r] : up[r];
                if (rs) un *= sc;
                up[r] = un;
                y[r] = un * xf[r];
            }
            nw0 = pack2bf(y[0], y[1]);
            nw1 = pack2bf(y[2], y[3]);
            if (rs) Cacc += klog;
        }

        u32* slot = reinterpret_cast<u32*>(&exchg[par ^ 1][ksw][l]) + 2*half;
        u32x2 nw2 = {nw0, nw1};
        *reinterpret_cast<u32x2*>(slot) = nw2;

        load_tile(ecur, mkcur, uE, uM);
        __builtin_amdgcn_sched_barrier(0xF); // ALU/VALU/SALU/MFMA may cross; VMEM+DS pinned
    };

    load_tile(eA, mkA, uEA, uMA);
    load_tile(eB, mkB, uEB, uMB);
    __builtin_amdgcn_sched_barrier(0xF);

    int m = 1;
    for (; m + 3 <= M; m += 4) {       // rs static: only (m+3)%4==0 rescales; par static
        iter(eA, mkA, uEA, uMA, false, 1);
        iter(eB, mkB, uEB, uMB, false, 0);
        iter(eA, mkA, uEA, uMA, false, 1);
        iter(eB, mkB, uEB, uMB, true,  0);
    }
    for (; m <= M; ++m) {              // bwd tail m=253..255 (never a rescale step)
        if (m & 1) iter(eA, mkA, uEA, uMA, false, 1);
        else       iter(eB, mkB, uEB, uMB, false, 0);
    }

    // final own state: fwd from ownprev regs, bwd from f32 up
    float* vrow = vws + ((size_t)(dir*Bn + batch))*Kn + bj + 8*g;
    f32x4 fv;
    if (dir) {
        fv = up;
    } else {
        fv[0] = __uint_as_float(ownprev0 << 16);
        fv[1] = __uint_as_float(ownprev0 & 0xffff0000u);
        fv[2] = __uint_as_float(ownprev1 << 16);
        fv[3] = __uint_as_float(ownprev1 & 0xffff0000u);
    }
    *reinterpret_cast<f32x4*>(vrow) = fv;
    if (mw == 0 && g == 0) Cws[dir*Bn + batch] = Cacc;
}

// ---------------- combine: numerator finalize + den + out accumulation ----------------
__global__ void crf_combine(const float* __restrict__ vws, const float* __restrict__ Cws,
                            const float* __restrict__ numpart, const int* __restrict__ cntpart,
                            const int* __restrict__ tags, const float* __restrict__ em,
                            const float* __restrict__ startT, const float* __restrict__ endT,
                            float* __restrict__ out)
{
    const int b = blockIdx.x;
    const int tid = threadIdx.x;
    const float p = vws[(size_t)b*Kn + tid] * vws[(size_t)(Bn + b)*Kn + tid];
    __shared__ float red[128];
    __shared__ float sp[NUMCH];
    __shared__ int   cp[NUMCH];
    red[tid] = p;
    if (tid < NUMCH) { sp[tid] = numpart[tid*Bn + b]; cp[tid] = cntpart[tid*Bn + b]; }
    __syncthreads();
    for (int off = 64; off > 0; off >>= 1) {
        if (tid < off) red[tid] += red[tid + off];
        __syncthreads();
    }
    if (tid == 0) {
        float s = 0.f; int cnt = 0;
        #pragma unroll
        for (int ch = 0; ch < NUMCH; ++ch) { s += sp[ch]; cnt += cp[ch]; }
        const int t0tag = tags[b];
        int seq_end = cnt - 1;
        if (seq_end < 0) seq_end = 0;
        const int lastTag = tags[seq_end*Bn + b];
        const float num = startT[t0tag] + em[(size_t)b*Kn + t0tag] + s + endT[lastTag];
        const float den = Cws[b] + Cws[Bn + b] + logf(red[0]);
        atomicAdd(out, num - den);
    }
}

extern "C" void kernel_launch(void* const* d_in, const int* in_sizes, int n_in,
                              void* d_out, int out_size, void* d_ws, size_t ws_size,
                              hipStream_t stream)
{
    const float* em     = (const float*)d_in[0];
    const int*   tags   = (const int*)d_in[1];
    const int*   mask   = (const int*)d_in[2];
    const float* startT = (const float*)d_in[3];
    const float* endT   = (const float*)d_in[4];
    const float* trans  = (const float*)d_in[5];

    char* ws = (char*)d_ws;
    bf16_t* frags   = (bf16_t*)ws;                      // 65536 B
    float*  Cws     = (float*)(ws + 65536);             // 4096 B
    float*  vws     = (float*)(ws + 69632);             // 524288 B
    float*  numpart = (float*)(ws + 593920);            // 32768 B
    int*    cntpart = (int*)(ws + 626688);              // 32768 B
    float*  out     = (float*)d_out;

    hipLaunchKernelGGL(crf_pre, dim3(2*NUMCH + 128), dim3(256), 0, stream,
                       em, tags, mask, trans, frags, numpart, cntpart, out);
    hipLaunchKernelGGL(crf_main, dim3(64), dim3(512), 0, stream,
                       em, mask, startT, endT, frags, vws, Cws);
    hipLaunchKernelGGL(crf_combine, dim3(Bn), dim3(128), 0, stream,
                       vws, Cws, numpart, cntpart, tags, em, startT, endT, out);
}